// Round 8
// baseline (413.522 us; speedup 1.0000x reference)
//
#include <hip/hip_runtime.h>
#include <hip/hip_bf16.h>

// ---------------------------------------------------------------------------
// GATv2 backbone, round 7 (resubmit after broker timeout):
//  - Layers 1-2 aggregate split BY HEAD with XCD pinning: head h -> blocks
//    bid%8 in {2h,2h+1}. Each XCD pair gathers only its 3.2MB head slice of
//    XL -> fits 4MiB per-XCD L2 (was 12.8MB thrash, FETCH 92MB @ 1.8TB/s).
//  - LN+ReLU becomes a separate cheap pass for layers 1-2 (head split breaks
//    the in-kernel fusion). Layer 3 (1 head) keeps the fused kernel.
//  - cursor zeroing folded into prep (memset dispatch dropped).
// ---------------------------------------------------------------------------

typedef __attribute__((ext_vector_type(8))) short bf16x8;
typedef __attribute__((ext_vector_type(4))) float f32x4;
typedef __attribute__((ext_vector_type(2))) float f32x2;

#define CAP 64   // bucket capacity (power of 2)

__device__ __forceinline__ ushort f2bf(float f) {
    unsigned u = __float_as_uint(f);
    unsigned r = (u + 0x7fffu + ((u >> 16) & 1u)) >> 16;
    return (ushort)r;
}
__device__ __forceinline__ f32x2 up2(unsigned u) {
    f32x2 r;
    r[0] = __uint_as_float(u << 16);
    r[1] = __uint_as_float(u & 0xffff0000u);
    return r;
}

// ---------------- prep: x->bf16 + 6x W transpose->bf16 + cursor zero ----------

__global__ __launch_bounds__(256) void prep_kernel(
    const float* __restrict__ x, ushort* __restrict__ xb, int n4,
    const float* W0, const float* W1, const float* W2,
    const float* W3, const float* W4, const float* W5,
    ushort* __restrict__ WT, int* __restrict__ cursor, int nzb, int n) {
    __shared__ ushort s[128 * 129];
    int tid = threadIdx.x;
    if (blockIdx.x < 6) {
        const float* Ws[6] = {W0, W1, W2, W3, W4, W5};
        const float* W = Ws[blockIdx.x];
        ushort* O = WT + blockIdx.x * 16384;
        for (int r = 0; r < 128; r += 2) {
            int k = r + (tid >> 7);
            int nn = tid & 127;
            s[nn * 129 + k] = f2bf(W[k * 128 + nn]);
        }
        __syncthreads();
        for (int i = tid; i < 16384; i += 256) {
            int nn = i >> 7, k = i & 127;
            O[i] = s[nn * 129 + k];
        }
    } else if (blockIdx.x < 6 + nzb) {
        int base = (blockIdx.x - 6) * 1024 + tid * 4;
        if (base + 3 < n) {
            *(int4*)&cursor[base] = make_int4(0, 0, 0, 0);
        } else {
            for (int j = 0; j < 4; ++j)
                if (base + j < n) cursor[base + j] = 0;
        }
    } else {
        int i = (blockIdx.x - 6 - nzb) * 256 + tid;
        if (i >= n4) return;
        float4 v = ((const float4*)x)[i];
        ushort4 o;
        o.x = f2bf(v.x); o.y = f2bf(v.y); o.z = f2bf(v.z); o.w = f2bf(v.w);
        ((ushort4*)xb)[i] = o;
    }
}

// ---------------- bucketed scatter (XCD-partitioned) ----------------

__global__ __launch_bounds__(256) void scatter_part_kernel(
    const int* __restrict__ srcrow, const int* __restrict__ dstrow,
    int E, int n, int* __restrict__ cursor, int* __restrict__ srcs) {
    int part = blockIdx.x & 7;
    int sub = blockIdx.x >> 3;
    int nsub = gridDim.x >> 3;
    int ppn = (n + 7) / 8;
    int lo = part * ppn;
    int hi = lo + ppn; if (hi > n) hi = n;
    int ET = E + n;
    int chunk = (ET + nsub - 1) / nsub;
    int s0 = sub * chunk, s1 = s0 + chunk; if (s1 > ET) s1 = ET;
    for (int i = s0 + threadIdx.x; i < s1; i += 256) {
        int d = (i < E) ? dstrow[i] : (i - E);
        if (d >= lo && d < hi) {
            int s = (i < E) ? srcrow[i] : (i - E);
            int pos = atomicAdd(&cursor[d], 1);
            if (pos < CAP) srcs[(d << 6) + pos] = s << 8;  // 256B per feature row
        }
    }
}

// ---------------- dual GEMM via MFMA ----------------

__global__ __launch_bounds__(256) void dual_gemm_mfma(
    const ushort* __restrict__ A,
    const ushort* __restrict__ WTl, const ushort* __restrict__ WTr,
    const float* __restrict__ bl, const float* __restrict__ br,
    ushort* __restrict__ XL, ushort* __restrict__ XR, int n) {
    int tid = threadIdx.x;
    int wid = tid >> 6, lane = tid & 63;
    int ln15 = lane & 15, hi = lane >> 4;
    int row0 = blockIdx.x * 64;

    const ushort* WT  = (wid < 2) ? WTl : WTr;
    const float* bias = (wid < 2) ? bl : br;
    ushort* OUT       = (wid < 2) ? XL : XR;
    int colbase = (wid & 1) * 64;

    float bv[4];
    #pragma unroll
    for (int nn = 0; nn < 4; ++nn) bv[nn] = bias[colbase + nn * 16 + ln15];

    f32x4 acc[4][4];
    #pragma unroll
    for (int m = 0; m < 4; ++m)
        #pragma unroll
        for (int nn = 0; nn < 4; ++nn) acc[m][nn] = (f32x4){0.f, 0.f, 0.f, 0.f};

    #pragma unroll
    for (int kk = 0; kk < 4; ++kk) {
        int kb = kk * 64 + hi * 16;
        bf16x8 a[4], b[4];
        #pragma unroll
        for (int m = 0; m < 4; ++m) {
            int r = row0 + m * 16 + ln15;
            a[m] = *(const bf16x8*)((const char*)A + (size_t)r * 256 + kb);
        }
        #pragma unroll
        for (int nn = 0; nn < 4; ++nn) {
            int c = colbase + nn * 16 + ln15;
            b[nn] = *(const bf16x8*)((const char*)WT + (size_t)c * 256 + kb);
        }
        #pragma unroll
        for (int m = 0; m < 4; ++m)
            #pragma unroll
            for (int nn = 0; nn < 4; ++nn)
                acc[m][nn] = __builtin_amdgcn_mfma_f32_16x16x32_bf16(a[m], b[nn], acc[m][nn], 0, 0, 0);
    }

    #pragma unroll
    for (int m = 0; m < 4; ++m) {
        int rbase = row0 + m * 16 + hi * 4;
        bool full = (rbase + 3 < n);
        #pragma unroll
        for (int nn = 0; nn < 4; ++nn) {
            int c = colbase + nn * 16 + ln15;
            ushort* o = OUT + (size_t)rbase * 128 + c;
            float b = bv[nn];
            __hip_bfloat162 h01 = __float22bfloat162_rn(make_float2(acc[m][nn][0] + b, acc[m][nn][1] + b));
            __hip_bfloat162 h23 = __float22bfloat162_rn(make_float2(acc[m][nn][2] + b, acc[m][nn][3] + b));
            ushort2 u01 = *(ushort2*)&h01;
            ushort2 u23 = *(ushort2*)&h23;
            if (full) {
                o[0] = u01.x; o[128] = u01.y; o[256] = u23.x; o[384] = u23.y;
            } else {
                if (rbase + 0 < n) o[0]   = u01.x;
                if (rbase + 1 < n) o[128] = u01.y;
                if (rbase + 2 < n) o[256] = u23.x;
                if (rbase + 3 < n) o[384] = u23.y;
            }
        }
    }
}

// ---------------- per-edge math (8 ch/lane as 4x f32x2) ----------------

template <int GS>
__device__ __forceinline__ void edge_op(uint4 U, const f32x2* xr, const f32x2* at,
                                        f32x2* acc, float& den) {
    f32x2 a0 = up2(U.x), a1 = up2(U.y), a2 = up2(U.z), a3 = up2(U.w);
    f32x2 t = a0 + xr[0];
    t = __builtin_elementwise_max(t, t * 0.2f);
    f32x2 dd = t * at[0];
    t = a1 + xr[1];
    t = __builtin_elementwise_max(t, t * 0.2f);
    dd = __builtin_elementwise_fma(t, at[1], dd);
    t = a2 + xr[2];
    t = __builtin_elementwise_max(t, t * 0.2f);
    dd = __builtin_elementwise_fma(t, at[2], dd);
    t = a3 + xr[3];
    t = __builtin_elementwise_max(t, t * 0.2f);
    dd = __builtin_elementwise_fma(t, at[3], dd);
    float p = dd[0] + dd[1];
    #pragma unroll
    for (int d = 1; d < GS; d <<= 1) p += __shfl_xor(p, d, 64);
    float ew = exp2f(p);
    f32x2 ev; ev[0] = ew; ev[1] = ew;
    acc[0] = __builtin_elementwise_fma(ev, a0, acc[0]);
    acc[1] = __builtin_elementwise_fma(ev, a1, acc[1]);
    acc[2] = __builtin_elementwise_fma(ev, a2, acc[2]);
    acc[3] = __builtin_elementwise_fma(ev, a3, acc[3]);
    den += ew;
}

// ---------------- head-split aggregate (layers 1-2, H=4) ----------------
// Head h owned by blocks with bid%8 in {2h,2h+1} (~XCD pair): gather working
// set = 3.2MB head slice, L2-resident. 4 lanes/node (8ch), 16 nodes/wave.
// Writes raw softmax-weighted sum + bias (LN in separate pass).

__global__ __launch_bounds__(256) void agg_head_kernel(
    const ushort* __restrict__ XL, const ushort* __restrict__ XR,
    const int* __restrict__ deg, const int* __restrict__ srcs,
    const float* __restrict__ att, const float* __restrict__ bias,
    ushort* __restrict__ OUT, int n) {
    int b = blockIdx.x;
    int head = (b & 7) >> 1;
    int s = ((b >> 3) << 1) | (b & 1);       // 0 .. nsub-1 within head
    int nsub = (gridDim.x >> 3) << 1;        // 512
    int tid = threadIdx.x;
    int wid = tid >> 6, lane = tid & 63;
    int ng = lane >> 2;                      // node slot 0..15
    int l4 = lane & 3;
    int hb = head * 64 + l4 * 16;            // byte offset of this lane's 16B
    int c0 = head * 32 + l4 * 8;             // channel index

    const char* XLc = (const char*)XL;

    f32x2 at[4];
    {
        const float4* ap = (const float4*)(att + c0);
        float4 a0 = ap[0], a1 = ap[1];
        at[0][0] = a0.x; at[0][1] = a0.y; at[1][0] = a0.z; at[1][1] = a0.w;
        at[2][0] = a1.x; at[2][1] = a1.y; at[3][0] = a1.z; at[3][1] = a1.w;
        #pragma unroll
        for (int j = 0; j < 4; ++j) at[j] = at[j] * 1.44269504f;  // log2(e)
    }
    f32x2 bi[4];
    {
        const f32x2* bp = (const f32x2*)(bias + c0);
        #pragma unroll
        for (int j = 0; j < 4; ++j) bi[j] = bp[j];
    }

    int npb = (n + nsub - 1) / nsub;
    int v0 = s * npb;
    int v1 = v0 + npb; if (v1 > n) v1 = n;

    for (int base = v0; base < v1; base += 64) {
        int node = base + wid * 16 + ng;
        bool alive = (node < v1);

        f32x2 xr[4];
        int e = 0;
        const int* sp = srcs;
        if (alive) {
            uint4 ur = *(const uint4*)((const char*)XR + ((size_t)node << 8) + hb);
            xr[0] = up2(ur.x); xr[1] = up2(ur.y); xr[2] = up2(ur.z); xr[3] = up2(ur.w);
            e = deg[node]; if (e > CAP) e = CAP;
            sp = srcs + ((size_t)node << 6);
        } else {
            #pragma unroll
            for (int j = 0; j < 4; ++j) { xr[j][0] = 0.f; xr[j][1] = 0.f; }
        }

        f32x2 acc[4];
        #pragma unroll
        for (int j = 0; j < 4; ++j) { acc[j][0] = 0.f; acc[j][1] = 0.f; }
        float den = 0.f;

        int i = 0;
        for (; i + 4 <= e; i += 4) {
            int4 ofs = *(const int4*)(sp + i);
            uint4 u0 = *(const uint4*)(XLc + ofs.x + hb);
            uint4 u1 = *(const uint4*)(XLc + ofs.y + hb);
            uint4 u2 = *(const uint4*)(XLc + ofs.z + hb);
            uint4 u3 = *(const uint4*)(XLc + ofs.w + hb);
            edge_op<4>(u0, xr, at, acc, den);
            edge_op<4>(u1, xr, at, acc, den);
            edge_op<4>(u2, xr, at, acc, den);
            edge_op<4>(u3, xr, at, acc, den);
        }
        for (; i < e; ++i) {
            uint4 u0 = *(const uint4*)(XLc + sp[i] + hb);
            edge_op<4>(u0, xr, at, acc, den);
        }

        if (alive) {
            float inv = 1.f / den;
            f32x2 iv; iv[0] = inv; iv[1] = inv;
            uint4 ov;
            unsigned* op = (unsigned*)&ov;
            #pragma unroll
            for (int j = 0; j < 4; ++j) {
                f32x2 o = __builtin_elementwise_fma(acc[j], iv, bi[j]);
                __hip_bfloat162 h = __float22bfloat162_rn(make_float2(o[0], o[1]));
                op[j] = *(unsigned*)&h;
            }
            *(uint4*)((char*)OUT + ((size_t)node << 8) + hb) = ov;
        }
    }
}

// ---------------- LN + ReLU pass (layers 1-2) ----------------
// 16 lanes/row (8 ch), 4 rows/wave, 16 rows/block. In-place on bf16 rows.

__global__ __launch_bounds__(256) void ln_relu_kernel(
    ushort* __restrict__ H, const float* __restrict__ gamma,
    const float* __restrict__ beta, int n) {
    int tid = threadIdx.x;
    int wid = tid >> 6, lane = tid & 63;
    int node = blockIdx.x * 16 + wid * 4 + (lane >> 4);
    int l = lane & 15, c0 = l * 8;
    bool alive = (node < n);

    f32x2 o[4];
    if (alive) {
        uint4 u = *(const uint4*)&H[(size_t)node * 128 + c0];
        o[0] = up2(u.x); o[1] = up2(u.y); o[2] = up2(u.z); o[3] = up2(u.w);
    } else {
        #pragma unroll
        for (int j = 0; j < 4; ++j) { o[j][0] = 0.f; o[j][1] = 0.f; }
    }

    float ssum = 0.f;
    #pragma unroll
    for (int j = 0; j < 4; ++j) ssum += o[j][0] + o[j][1];
    #pragma unroll
    for (int d = 1; d < 16; d <<= 1) ssum += __shfl_xor(ssum, d, 64);
    float mu = ssum * (1.f / 128.f);
    float vsum = 0.f;
    #pragma unroll
    for (int j = 0; j < 4; ++j) {
        float d0 = o[j][0] - mu, d1 = o[j][1] - mu;
        vsum += d0 * d0 + d1 * d1;
    }
    #pragma unroll
    for (int d = 1; d < 16; d <<= 1) vsum += __shfl_xor(vsum, d, 64);
    float rstd = rsqrtf(vsum * (1.f / 128.f) + 1e-5f);

    if (!alive) return;

    const f32x2* gp = (const f32x2*)(gamma + c0);
    const f32x2* ep = (const f32x2*)(beta + c0);
    uint4 ov;
    unsigned* op = (unsigned*)&ov;
    #pragma unroll
    for (int j = 0; j < 4; ++j) {
        f32x2 gj = gp[j], bj = ep[j];
        float y0 = fmaxf(fmaf((o[j][0] - mu) * rstd, gj[0], bj[0]), 0.f);
        float y1 = fmaxf(fmaf((o[j][1] - mu) * rstd, gj[1], bj[1]), 0.f);
        __hip_bfloat162 h = __float22bfloat162_rn(make_float2(y0, y1));
        op[j] = *(unsigned*)&h;
    }
    *(uint4*)&H[(size_t)node * 128 + c0] = ov;
}

// ---------------- layer-3 fused aggregate (H=1) + LN + ReLU ----------------

template <int H, bool OUT_BF16>
__global__ __launch_bounds__(256) void aggregate_kernel(
    const ushort* __restrict__ XL, const ushort* __restrict__ XR,
    const int* __restrict__ deg, const int* __restrict__ srcs,
    const float* __restrict__ att, const float* __restrict__ bias,
    const float* __restrict__ gamma, const float* __restrict__ beta,
    void* __restrict__ OUTP, int n) {
    int tid = threadIdx.x;
    int wid = tid >> 6, lane = tid & 63;
    int g = lane >> 4, l = lane & 15;
    int node = blockIdx.x * 16 + wid * 4 + g;
    bool alive = (node < n);
    int c0 = l * 8;
    constexpr int GS = (128 / H) / 8;

    const char* XLc = (const char*)XL;
    int lb = l * 16;

    f32x2 at[4];
    {
        const float4* ap = (const float4*)(att + c0);
        float4 a0 = ap[0], a1 = ap[1];
        at[0][0] = a0.x; at[0][1] = a0.y; at[1][0] = a0.z; at[1][1] = a0.w;
        at[2][0] = a1.x; at[2][1] = a1.y; at[3][0] = a1.z; at[3][1] = a1.w;
        #pragma unroll
        for (int j = 0; j < 4; ++j) at[j] = at[j] * 1.44269504f;
    }

    f32x2 xr[4];
    int e = 0;
    const int* sp = srcs;
    if (alive) {
        uint4 ur = *(const uint4*)((const char*)XR + ((size_t)node << 8) + lb);
        xr[0] = up2(ur.x); xr[1] = up2(ur.y); xr[2] = up2(ur.z); xr[3] = up2(ur.w);
        e = deg[node]; if (e > CAP) e = CAP;
        sp = srcs + ((size_t)node << 6);
    } else {
        #pragma unroll
        for (int j = 0; j < 4; ++j) { xr[j][0] = 0.f; xr[j][1] = 0.f; }
    }

    f32x2 acc[4];
    #pragma unroll
    for (int j = 0; j < 4; ++j) { acc[j][0] = 0.f; acc[j][1] = 0.f; }
    float den = 0.f;

    int i = 0;
    for (; i + 4 <= e; i += 4) {
        int4 ofs = *(const int4*)(sp + i);
        uint4 u0 = *(const uint4*)(XLc + ofs.x + lb);
        uint4 u1 = *(const uint4*)(XLc + ofs.y + lb);
        uint4 u2 = *(const uint4*)(XLc + ofs.z + lb);
        uint4 u3 = *(const uint4*)(XLc + ofs.w + lb);
        edge_op<GS>(u0, xr, at, acc, den);
        edge_op<GS>(u1, xr, at, acc, den);
        edge_op<GS>(u2, xr, at, acc, den);
        edge_op<GS>(u3, xr, at, acc, den);
    }
    for (; i < e; ++i) {
        uint4 u0 = *(const uint4*)(XLc + sp[i] + lb);
        edge_op<GS>(u0, xr, at, acc, den);
    }

    float inv = 1.f / den;
    f32x2 o[4];
    {
        const f32x2* bp = (const f32x2*)(bias + c0);
        f32x2 iv; iv[0] = inv; iv[1] = inv;
        #pragma unroll
        for (int j = 0; j < 4; ++j) o[j] = __builtin_elementwise_fma(acc[j], iv, bp[j]);
    }

    float ssum = 0.f;
    #pragma unroll
    for (int j = 0; j < 4; ++j) ssum += o[j][0] + o[j][1];
    #pragma unroll
    for (int d = 1; d < 16; d <<= 1) ssum += __shfl_xor(ssum, d, 64);
    float mu = ssum * (1.f / 128.f);
    float vsum = 0.f;
    #pragma unroll
    for (int j = 0; j < 4; ++j) {
        float d0 = o[j][0] - mu, d1 = o[j][1] - mu;
        vsum += d0 * d0 + d1 * d1;
    }
    #pragma unroll
    for (int d = 1; d < 16; d <<= 1) vsum += __shfl_xor(vsum, d, 64);
    float rstd = rsqrtf(vsum * (1.f / 128.f) + 1e-5f);

    if (!alive) return;

    const f32x2* gp = (const f32x2*)(gamma + c0);
    const f32x2* ep = (const f32x2*)(beta + c0);
    float y[8];
    #pragma unroll
    for (int j = 0; j < 4; ++j) {
        f32x2 gj = gp[j], bj = ep[j];
        y[2 * j]     = fmaxf(fmaf((o[j][0] - mu) * rstd, gj[0], bj[0]), 0.f);
        y[2 * j + 1] = fmaxf(fmaf((o[j][1] - mu) * rstd, gj[1], bj[1]), 0.f);
    }

    if (OUT_BF16) {
        __hip_bfloat162 h0 = __float22bfloat162_rn(make_float2(y[0], y[1]));
        __hip_bfloat162 h1 = __float22bfloat162_rn(make_float2(y[2], y[3]));
        __hip_bfloat162 h2 = __float22bfloat162_rn(make_float2(y[4], y[5]));
        __hip_bfloat162 h3 = __float22bfloat162_rn(make_float2(y[6], y[7]));
        uint4 ov;
        ov.x = *(unsigned*)&h0; ov.y = *(unsigned*)&h1;
        ov.z = *(unsigned*)&h2; ov.w = *(unsigned*)&h3;
        *(uint4*)&((ushort*)OUTP)[(size_t)node * 128 + c0] = ov;
    } else {
        float* O = (float*)OUTP + (size_t)node * 128 + c0;
        *(float4*)O = make_float4(y[0], y[1], y[2], y[3]);
        *(float4*)(O + 4) = make_float4(y[4], y[5], y[6], y[7]);
    }
}

// ---------------- launch ----------------

extern "C" void kernel_launch(void* const* d_in, const int* in_sizes, int n_in,
                              void* d_out, int out_size, void* d_ws, size_t ws_size,
                              hipStream_t stream) {
    const float* x  = (const float*)d_in[0];
    const int*   ei = (const int*)d_in[1];
    const float *W1l = (const float*)d_in[2],  *b1l = (const float*)d_in[3];
    const float *W1r = (const float*)d_in[4],  *b1r = (const float*)d_in[5];
    const float *a1  = (const float*)d_in[6],  *c1  = (const float*)d_in[7];
    const float *g1  = (const float*)d_in[8],  *be1 = (const float*)d_in[9];
    const float *W2l = (const float*)d_in[10], *b2l = (const float*)d_in[11];
    const float *W2r = (const float*)d_in[12], *b2r = (const float*)d_in[13];
    const float *a2  = (const float*)d_in[14], *c2  = (const float*)d_in[15];
    const float *g2  = (const float*)d_in[16], *be2 = (const float*)d_in[17];
    const float *W3l = (const float*)d_in[18], *b3l = (const float*)d_in[19];
    const float *W3r = (const float*)d_in[20], *b3r = (const float*)d_in[21];
    const float *a3  = (const float*)d_in[22], *c3  = (const float*)d_in[23];
    const float *g3  = (const float*)d_in[24], *be3 = (const float*)d_in[25];

    int n  = in_sizes[0] / 128;
    int E  = in_sizes[1] / 2;
    size_t nPad = (size_t)((n + 63) / 64) * 64;

    char* ws = (char*)d_ws;
    ushort* xb = (ushort*)ws;                      ws += nPad * 128 * 2;
    ushort* XL = (ushort*)ws;                      ws += nPad * 128 * 2;
    ushort* XR = (ushort*)ws;                      ws += nPad * 128 * 2;
    ushort* hb = (ushort*)ws;                      ws += nPad * 128 * 2;
    ushort* WT = (ushort*)ws;                      ws += 6 * 16384 * 2;
    int* cursor = (int*)ws;                        ws += (size_t)n * 4;
    int* srcs   = (int*)ws;                        // n * CAP ints (12.8 MB)

    const int* srcrow = ei;
    const int* dstrow = ei + E;

    // prep: x->bf16 + 6 weight transposes + cursor zeroing
    int n4 = n * 128 / 4;
    int nzb = (n + 1023) / 1024;
    prep_kernel<<<6 + nzb + (n4 + 255) / 256, 256, 0, stream>>>(
        x, xb, n4, W1l, W1r, W2l, W2r, W3l, W3r, WT, cursor, nzb, n);

    // bucketed scatter (XCD-partitioned)
    scatter_part_kernel<<<2048, 256, 0, stream>>>(srcrow, dstrow, E, n, cursor, srcs);

    int gb = (int)(nPad / 64);
    int ab = (n + 15) / 16;

    // layer 1
    dual_gemm_mfma<<<gb, 256, 0, stream>>>(xb, WT + 0 * 16384, WT + 1 * 16384, b1l, b1r, XL, XR, n);
    agg_head_kernel<<<2048, 256, 0, stream>>>(XL, XR, cursor, srcs, a1, c1, hb, n);
    ln_relu_kernel<<<ab, 256, 0, stream>>>(hb, g1, be1, n);
    // layer 2
    dual_gemm_mfma<<<gb, 256, 0, stream>>>(hb, WT + 2 * 16384, WT + 3 * 16384, b2l, b2r, XL, XR, n);
    agg_head_kernel<<<2048, 256, 0, stream>>>(XL, XR, cursor, srcs, a2, c2, hb, n);
    ln_relu_kernel<<<ab, 256, 0, stream>>>(hb, g2, be2, n);
    // layer 3 (1 head, fused LN)
    dual_gemm_mfma<<<gb, 256, 0, stream>>>(hb, WT + 4 * 16384, WT + 5 * 16384, b3l, b3r, XL, XR, n);
    aggregate_kernel<1, false><<<ab, 256, 0, stream>>>(XL, XR, cursor, srcs, a3, c3, g3, be3, d_out, n);
}

// Round 9
// 407.339 us; speedup vs baseline: 1.0152x; 1.0152x over previous
//
#include <hip/hip_runtime.h>
#include <hip/hip_bf16.h>

// ---------------------------------------------------------------------------
// GATv2 backbone, round 9:
//  - HEAD-MAJOR XL/XR layout: XL_hm[head][nPad][32ch] (contiguous 3.2MB per
//    head). Fixes round-8 regression: row-major head slices straddled 128B L2
//    lines -> 512B/edge HBM traffic. Now head h's gather working set is a
//    contiguous 3.2MB block, L2-resident per XCD pair.
//  - agg_head (layers 1-2): head h -> blocks bid%8 in {2h,2h+1} (XCD pinned).
//  - layer 3 reads head-major via per-lane base ((l>>2)*slice + (l&3)*16);
//    channel<->lane map identical (c0 = l*8), math unchanged.
//  - srcs stores node<<6 (byte offset into a head slice).
// ---------------------------------------------------------------------------

typedef __attribute__((ext_vector_type(8))) short bf16x8;
typedef __attribute__((ext_vector_type(4))) float f32x4;
typedef __attribute__((ext_vector_type(2))) float f32x2;

#define CAP 64   // bucket capacity (power of 2)

__device__ __forceinline__ ushort f2bf(float f) {
    unsigned u = __float_as_uint(f);
    unsigned r = (u + 0x7fffu + ((u >> 16) & 1u)) >> 16;
    return (ushort)r;
}
__device__ __forceinline__ f32x2 up2(unsigned u) {
    f32x2 r;
    r[0] = __uint_as_float(u << 16);
    r[1] = __uint_as_float(u & 0xffff0000u);
    return r;
}

// ---------------- prep: x->bf16 + 6x W transpose->bf16 + cursor zero ----------

__global__ __launch_bounds__(256) void prep_kernel(
    const float* __restrict__ x, ushort* __restrict__ xb, int n4,
    const float* W0, const float* W1, const float* W2,
    const float* W3, const float* W4, const float* W5,
    ushort* __restrict__ WT, int* __restrict__ cursor, int nzb, int n) {
    __shared__ ushort s[128 * 129];
    int tid = threadIdx.x;
    if (blockIdx.x < 6) {
        const float* Ws[6] = {W0, W1, W2, W3, W4, W5};
        const float* W = Ws[blockIdx.x];
        ushort* O = WT + blockIdx.x * 16384;
        for (int r = 0; r < 128; r += 2) {
            int k = r + (tid >> 7);
            int nn = tid & 127;
            s[nn * 129 + k] = f2bf(W[k * 128 + nn]);
        }
        __syncthreads();
        for (int i = tid; i < 16384; i += 256) {
            int nn = i >> 7, k = i & 127;
            O[i] = s[nn * 129 + k];
        }
    } else if (blockIdx.x < 6 + nzb) {
        int base = (blockIdx.x - 6) * 1024 + tid * 4;
        if (base + 3 < n) {
            *(int4*)&cursor[base] = make_int4(0, 0, 0, 0);
        } else {
            for (int j = 0; j < 4; ++j)
                if (base + j < n) cursor[base + j] = 0;
        }
    } else {
        int i = (blockIdx.x - 6 - nzb) * 256 + tid;
        if (i >= n4) return;
        float4 v = ((const float4*)x)[i];
        ushort4 o;
        o.x = f2bf(v.x); o.y = f2bf(v.y); o.z = f2bf(v.z); o.w = f2bf(v.w);
        ((ushort4*)xb)[i] = o;
    }
}

// ---------------- bucketed scatter (XCD-partitioned) ----------------

__global__ __launch_bounds__(256) void scatter_part_kernel(
    const int* __restrict__ srcrow, const int* __restrict__ dstrow,
    int E, int n, int* __restrict__ cursor, int* __restrict__ srcs) {
    int part = blockIdx.x & 7;
    int sub = blockIdx.x >> 3;
    int nsub = gridDim.x >> 3;
    int ppn = (n + 7) / 8;
    int lo = part * ppn;
    int hi = lo + ppn; if (hi > n) hi = n;
    int ET = E + n;
    int chunk = (ET + nsub - 1) / nsub;
    int s0 = sub * chunk, s1 = s0 + chunk; if (s1 > ET) s1 = ET;
    for (int i = s0 + threadIdx.x; i < s1; i += 256) {
        int d = (i < E) ? dstrow[i] : (i - E);
        if (d >= lo && d < hi) {
            int s = (i < E) ? srcrow[i] : (i - E);
            int pos = atomicAdd(&cursor[d], 1);
            if (pos < CAP) srcs[(d << 6) + pos] = s << 6;  // 64B head-slice row
        }
    }
}

// ---------------- dual GEMM via MFMA, head-major epilogue ----------------
// Writes OUT_hm[head][nPad][32]: col c -> head c>>5, within-head c&31.

__global__ __launch_bounds__(256) void dual_gemm_mfma(
    const ushort* __restrict__ A,
    const ushort* __restrict__ WTl, const ushort* __restrict__ WTr,
    const float* __restrict__ bl, const float* __restrict__ br,
    ushort* __restrict__ XL, ushort* __restrict__ XR, int n, int sliceE) {
    int tid = threadIdx.x;
    int wid = tid >> 6, lane = tid & 63;
    int ln15 = lane & 15, hi = lane >> 4;
    int row0 = blockIdx.x * 64;

    const ushort* WT  = (wid < 2) ? WTl : WTr;
    const float* bias = (wid < 2) ? bl : br;
    ushort* OUT       = (wid < 2) ? XL : XR;
    int colbase = (wid & 1) * 64;

    float bv[4];
    #pragma unroll
    for (int nn = 0; nn < 4; ++nn) bv[nn] = bias[colbase + nn * 16 + ln15];

    f32x4 acc[4][4];
    #pragma unroll
    for (int m = 0; m < 4; ++m)
        #pragma unroll
        for (int nn = 0; nn < 4; ++nn) acc[m][nn] = (f32x4){0.f, 0.f, 0.f, 0.f};

    #pragma unroll
    for (int kk = 0; kk < 4; ++kk) {
        int kb = kk * 64 + hi * 16;
        bf16x8 a[4], b[4];
        #pragma unroll
        for (int m = 0; m < 4; ++m) {
            int r = row0 + m * 16 + ln15;
            a[m] = *(const bf16x8*)((const char*)A + (size_t)r * 256 + kb);
        }
        #pragma unroll
        for (int nn = 0; nn < 4; ++nn) {
            int c = colbase + nn * 16 + ln15;
            b[nn] = *(const bf16x8*)((const char*)WT + (size_t)c * 256 + kb);
        }
        #pragma unroll
        for (int m = 0; m < 4; ++m)
            #pragma unroll
            for (int nn = 0; nn < 4; ++nn)
                acc[m][nn] = __builtin_amdgcn_mfma_f32_16x16x32_bf16(a[m], b[nn], acc[m][nn], 0, 0, 0);
    }

    #pragma unroll
    for (int m = 0; m < 4; ++m) {
        int rbase = row0 + m * 16 + hi * 4;
        bool full = (rbase + 3 < n);
        #pragma unroll
        for (int nn = 0; nn < 4; ++nn) {
            int c = colbase + nn * 16;                       // + ln15
            int head = c >> 5;
            ushort* o = OUT + (size_t)head * sliceE + (size_t)rbase * 32
                            + (nn & 1) * 16 + ln15;
            float b = bv[nn];
            __hip_bfloat162 h01 = __float22bfloat162_rn(make_float2(acc[m][nn][0] + b, acc[m][nn][1] + b));
            __hip_bfloat162 h23 = __float22bfloat162_rn(make_float2(acc[m][nn][2] + b, acc[m][nn][3] + b));
            ushort2 u01 = *(ushort2*)&h01;
            ushort2 u23 = *(ushort2*)&h23;
            if (full) {
                o[0] = u01.x; o[32] = u01.y; o[64] = u23.x; o[96] = u23.y;
            } else {
                if (rbase + 0 < n) o[0]  = u01.x;
                if (rbase + 1 < n) o[32] = u01.y;
                if (rbase + 2 < n) o[64] = u23.x;
                if (rbase + 3 < n) o[96] = u23.y;
            }
        }
    }
}

// ---------------- per-edge math (8 ch/lane as 4x f32x2) ----------------

template <int GS>
__device__ __forceinline__ void edge_op(uint4 U, const f32x2* xr, const f32x2* at,
                                        f32x2* acc, float& den) {
    f32x2 a0 = up2(U.x), a1 = up2(U.y), a2 = up2(U.z), a3 = up2(U.w);
    f32x2 t = a0 + xr[0];
    t = __builtin_elementwise_max(t, t * 0.2f);
    f32x2 dd = t * at[0];
    t = a1 + xr[1];
    t = __builtin_elementwise_max(t, t * 0.2f);
    dd = __builtin_elementwise_fma(t, at[1], dd);
    t = a2 + xr[2];
    t = __builtin_elementwise_max(t, t * 0.2f);
    dd = __builtin_elementwise_fma(t, at[2], dd);
    t = a3 + xr[3];
    t = __builtin_elementwise_max(t, t * 0.2f);
    dd = __builtin_elementwise_fma(t, at[3], dd);
    float p = dd[0] + dd[1];
    #pragma unroll
    for (int d = 1; d < GS; d <<= 1) p += __shfl_xor(p, d, 64);
    float ew = exp2f(p);
    f32x2 ev; ev[0] = ew; ev[1] = ew;
    acc[0] = __builtin_elementwise_fma(ev, a0, acc[0]);
    acc[1] = __builtin_elementwise_fma(ev, a1, acc[1]);
    acc[2] = __builtin_elementwise_fma(ev, a2, acc[2]);
    acc[3] = __builtin_elementwise_fma(ev, a3, acc[3]);
    den += ew;
}

// ---------------- head-split aggregate (layers 1-2, H=4) ----------------
// Head h owned by blocks bid%8 in {2h,2h+1}; XL/XR head-major. Output
// row-major (+bias), LN in separate pass.

__global__ __launch_bounds__(256) void agg_head_kernel(
    const ushort* __restrict__ XL, const ushort* __restrict__ XR,
    const int* __restrict__ deg, const int* __restrict__ srcs,
    const float* __restrict__ att, const float* __restrict__ bias,
    ushort* __restrict__ OUT, int n, int sliceB) {
    int b = blockIdx.x;
    int head = (b & 7) >> 1;
    int s = ((b >> 3) << 1) | (b & 1);       // 0 .. nsub-1 within head
    int nsub = (gridDim.x >> 3) << 1;        // 512
    int tid = threadIdx.x;
    int wid = tid >> 6, lane = tid & 63;
    int ng = lane >> 2;                      // node slot 0..15
    int l4 = lane & 3;
    int c0 = head * 32 + l4 * 8;             // channel index

    const char* XLb = (const char*)XL + (size_t)head * sliceB + l4 * 16;
    const char* XRb = (const char*)XR + (size_t)head * sliceB + l4 * 16;

    f32x2 at[4];
    {
        const float4* ap = (const float4*)(att + c0);
        float4 a0 = ap[0], a1 = ap[1];
        at[0][0] = a0.x; at[0][1] = a0.y; at[1][0] = a0.z; at[1][1] = a0.w;
        at[2][0] = a1.x; at[2][1] = a1.y; at[3][0] = a1.z; at[3][1] = a1.w;
        #pragma unroll
        for (int j = 0; j < 4; ++j) at[j] = at[j] * 1.44269504f;  // log2(e)
    }
    f32x2 bi[4];
    {
        const f32x2* bp = (const f32x2*)(bias + c0);
        #pragma unroll
        for (int j = 0; j < 4; ++j) bi[j] = bp[j];
    }

    int npb = (n + nsub - 1) / nsub;
    int v0 = s * npb;
    int v1 = v0 + npb; if (v1 > n) v1 = n;

    for (int base = v0; base < v1; base += 64) {
        int node = base + wid * 16 + ng;
        bool alive = (node < v1);

        f32x2 xr[4];
        int e = 0;
        const int* sp = srcs;
        if (alive) {
            uint4 ur = *(const uint4*)(XRb + ((size_t)node << 6));
            xr[0] = up2(ur.x); xr[1] = up2(ur.y); xr[2] = up2(ur.z); xr[3] = up2(ur.w);
            e = deg[node]; if (e > CAP) e = CAP;
            sp = srcs + ((size_t)node << 6);
        } else {
            #pragma unroll
            for (int j = 0; j < 4; ++j) { xr[j][0] = 0.f; xr[j][1] = 0.f; }
        }

        f32x2 acc[4];
        #pragma unroll
        for (int j = 0; j < 4; ++j) { acc[j][0] = 0.f; acc[j][1] = 0.f; }
        float den = 0.f;

        int i = 0;
        for (; i + 4 <= e; i += 4) {
            int4 ofs = *(const int4*)(sp + i);
            uint4 u0 = *(const uint4*)(XLb + ofs.x);
            uint4 u1 = *(const uint4*)(XLb + ofs.y);
            uint4 u2 = *(const uint4*)(XLb + ofs.z);
            uint4 u3 = *(const uint4*)(XLb + ofs.w);
            edge_op<4>(u0, xr, at, acc, den);
            edge_op<4>(u1, xr, at, acc, den);
            edge_op<4>(u2, xr, at, acc, den);
            edge_op<4>(u3, xr, at, acc, den);
        }
        for (; i < e; ++i) {
            uint4 u0 = *(const uint4*)(XLb + sp[i]);
            edge_op<4>(u0, xr, at, acc, den);
        }

        if (alive) {
            float inv = 1.f / den;
            f32x2 iv; iv[0] = inv; iv[1] = inv;
            uint4 ov;
            unsigned* op = (unsigned*)&ov;
            #pragma unroll
            for (int j = 0; j < 4; ++j) {
                f32x2 o = __builtin_elementwise_fma(acc[j], iv, bi[j]);
                __hip_bfloat162 h = __float22bfloat162_rn(make_float2(o[0], o[1]));
                op[j] = *(unsigned*)&h;
            }
            // row-major output: node*256B + c0*2B
            *(uint4*)((char*)OUT + ((size_t)node << 8) + c0 * 2) = ov;
        }
    }
}

// ---------------- LN + ReLU pass (layers 1-2) ----------------

__global__ __launch_bounds__(256) void ln_relu_kernel(
    ushort* __restrict__ H, const float* __restrict__ gamma,
    const float* __restrict__ beta, int n) {
    int tid = threadIdx.x;
    int wid = tid >> 6, lane = tid & 63;
    int node = blockIdx.x * 16 + wid * 4 + (lane >> 4);
    int l = lane & 15, c0 = l * 8;
    bool alive = (node < n);

    f32x2 o[4];
    if (alive) {
        uint4 u = *(const uint4*)&H[(size_t)node * 128 + c0];
        o[0] = up2(u.x); o[1] = up2(u.y); o[2] = up2(u.z); o[3] = up2(u.w);
    } else {
        #pragma unroll
        for (int j = 0; j < 4; ++j) { o[j][0] = 0.f; o[j][1] = 0.f; }
    }

    float ssum = 0.f;
    #pragma unroll
    for (int j = 0; j < 4; ++j) ssum += o[j][0] + o[j][1];
    #pragma unroll
    for (int d = 1; d < 16; d <<= 1) ssum += __shfl_xor(ssum, d, 64);
    float mu = ssum * (1.f / 128.f);
    float vsum = 0.f;
    #pragma unroll
    for (int j = 0; j < 4; ++j) {
        float d0 = o[j][0] - mu, d1 = o[j][1] - mu;
        vsum += d0 * d0 + d1 * d1;
    }
    #pragma unroll
    for (int d = 1; d < 16; d <<= 1) vsum += __shfl_xor(vsum, d, 64);
    float rstd = rsqrtf(vsum * (1.f / 128.f) + 1e-5f);

    if (!alive) return;

    const f32x2* gp = (const f32x2*)(gamma + c0);
    const f32x2* ep = (const f32x2*)(beta + c0);
    uint4 ov;
    unsigned* op = (unsigned*)&ov;
    #pragma unroll
    for (int j = 0; j < 4; ++j) {
        f32x2 gj = gp[j], bj = ep[j];
        float y0 = fmaxf(fmaf((o[j][0] - mu) * rstd, gj[0], bj[0]), 0.f);
        float y1 = fmaxf(fmaf((o[j][1] - mu) * rstd, gj[1], bj[1]), 0.f);
        __hip_bfloat162 h = __float22bfloat162_rn(make_float2(y0, y1));
        op[j] = *(unsigned*)&h;
    }
    *(uint4*)&H[(size_t)node * 128 + c0] = ov;
}

// ---------------- layer-3 fused aggregate (H=1) + LN + ReLU ----------------
// Reads head-major XL/XR: lane l -> head l>>2, sub l&3; c0 = l*8 unchanged.

__global__ __launch_bounds__(256) void aggregate3_kernel(
    const ushort* __restrict__ XL, const ushort* __restrict__ XR,
    const int* __restrict__ deg, const int* __restrict__ srcs,
    const float* __restrict__ att, const float* __restrict__ bias,
    const float* __restrict__ gamma, const float* __restrict__ beta,
    float* __restrict__ OUTP, int n, int sliceB) {
    int tid = threadIdx.x;
    int wid = tid >> 6, lane = tid & 63;
    int g = lane >> 4, l = lane & 15;
    int node = blockIdx.x * 16 + wid * 4 + g;
    bool alive = (node < n);
    int c0 = l * 8;

    const char* XLb = (const char*)XL + (size_t)(l >> 2) * sliceB + (l & 3) * 16;
    const char* XRb = (const char*)XR + (size_t)(l >> 2) * sliceB + (l & 3) * 16;

    f32x2 at[4];
    {
        const float4* ap = (const float4*)(att + c0);
        float4 a0 = ap[0], a1 = ap[1];
        at[0][0] = a0.x; at[0][1] = a0.y; at[1][0] = a0.z; at[1][1] = a0.w;
        at[2][0] = a1.x; at[2][1] = a1.y; at[3][0] = a1.z; at[3][1] = a1.w;
        #pragma unroll
        for (int j = 0; j < 4; ++j) at[j] = at[j] * 1.44269504f;
    }

    f32x2 xr[4];
    int e = 0;
    const int* sp = srcs;
    if (alive) {
        uint4 ur = *(const uint4*)(XRb + ((size_t)node << 6));
        xr[0] = up2(ur.x); xr[1] = up2(ur.y); xr[2] = up2(ur.z); xr[3] = up2(ur.w);
        e = deg[node]; if (e > CAP) e = CAP;
        sp = srcs + ((size_t)node << 6);
    } else {
        #pragma unroll
        for (int j = 0; j < 4; ++j) { xr[j][0] = 0.f; xr[j][1] = 0.f; }
    }

    f32x2 acc[4];
    #pragma unroll
    for (int j = 0; j < 4; ++j) { acc[j][0] = 0.f; acc[j][1] = 0.f; }
    float den = 0.f;

    int i = 0;
    for (; i + 4 <= e; i += 4) {
        int4 ofs = *(const int4*)(sp + i);
        uint4 u0 = *(const uint4*)(XLb + ofs.x);
        uint4 u1 = *(const uint4*)(XLb + ofs.y);
        uint4 u2 = *(const uint4*)(XLb + ofs.z);
        uint4 u3 = *(const uint4*)(XLb + ofs.w);
        edge_op<16>(u0, xr, at, acc, den);
        edge_op<16>(u1, xr, at, acc, den);
        edge_op<16>(u2, xr, at, acc, den);
        edge_op<16>(u3, xr, at, acc, den);
    }
    for (; i < e; ++i) {
        uint4 u0 = *(const uint4*)(XLb + sp[i]);
        edge_op<16>(u0, xr, at, acc, den);
    }

    float inv = 1.f / den;
    f32x2 o[4];
    {
        const f32x2* bp = (const f32x2*)(bias + c0);
        f32x2 iv; iv[0] = inv; iv[1] = inv;
        #pragma unroll
        for (int j = 0; j < 4; ++j) o[j] = __builtin_elementwise_fma(acc[j], iv, bp[j]);
    }

    float ssum = 0.f;
    #pragma unroll
    for (int j = 0; j < 4; ++j) ssum += o[j][0] + o[j][1];
    #pragma unroll
    for (int d = 1; d < 16; d <<= 1) ssum += __shfl_xor(ssum, d, 64);
    float mu = ssum * (1.f / 128.f);
    float vsum = 0.f;
    #pragma unroll
    for (int j = 0; j < 4; ++j) {
        float d0 = o[j][0] - mu, d1 = o[j][1] - mu;
        vsum += d0 * d0 + d1 * d1;
    }
    #pragma unroll
    for (int d = 1; d < 16; d <<= 1) vsum += __shfl_xor(vsum, d, 64);
    float rstd = rsqrtf(vsum * (1.f / 128.f) + 1e-5f);

    if (!alive) return;

    const f32x2* gp = (const f32x2*)(gamma + c0);
    const f32x2* ep = (const f32x2*)(beta + c0);
    float y[8];
    #pragma unroll
    for (int j = 0; j < 4; ++j) {
        f32x2 gj = gp[j], bj = ep[j];
        y[2 * j]     = fmaxf(fmaf((o[j][0] - mu) * rstd, gj[0], bj[0]), 0.f);
        y[2 * j + 1] = fmaxf(fmaf((o[j][1] - mu) * rstd, gj[1], bj[1]), 0.f);
    }

    float* O = OUTP + (size_t)node * 128 + c0;
    *(float4*)O = make_float4(y[0], y[1], y[2], y[3]);
    *(float4*)(O + 4) = make_float4(y[4], y[5], y[6], y[7]);
}

// ---------------- launch ----------------

extern "C" void kernel_launch(void* const* d_in, const int* in_sizes, int n_in,
                              void* d_out, int out_size, void* d_ws, size_t ws_size,
                              hipStream_t stream) {
    const float* x  = (const float*)d_in[0];
    const int*   ei = (const int*)d_in[1];
    const float *W1l = (const float*)d_in[2],  *b1l = (const float*)d_in[3];
    const float *W1r = (const float*)d_in[4],  *b1r = (const float*)d_in[5];
    const float *a1  = (const float*)d_in[6],  *c1  = (const float*)d_in[7];
    const float *g1  = (const float*)d_in[8],  *be1 = (const float*)d_in[9];
    const float *W2l = (const float*)d_in[10], *b2l = (const float*)d_in[11];
    const float *W2r = (const float*)d_in[12], *b2r = (const float*)d_in[13];
    const float *a2  = (const float*)d_in[14], *c2  = (const float*)d_in[15];
    const float *g2  = (const float*)d_in[16], *be2 = (const float*)d_in[17];
    const float *W3l = (const float*)d_in[18], *b3l = (const float*)d_in[19];
    const float *W3r = (const float*)d_in[20], *b3r = (const float*)d_in[21];
    const float *a3  = (const float*)d_in[22], *c3  = (const float*)d_in[23];
    const float *g3  = (const float*)d_in[24], *be3 = (const float*)d_in[25];

    int n  = in_sizes[0] / 128;
    int E  = in_sizes[1] / 2;
    size_t nPad = (size_t)((n + 63) / 64) * 64;
    int sliceE = (int)(nPad * 32);      // ushort elements per head slice
    int sliceB = (int)(nPad * 64);      // bytes per head slice

    char* ws = (char*)d_ws;
    ushort* xb = (ushort*)ws;                      ws += nPad * 128 * 2;
    ushort* XL = (ushort*)ws;                      ws += nPad * 128 * 2;
    ushort* XR = (ushort*)ws;                      ws += nPad * 128 * 2;
    ushort* hb = (ushort*)ws;                      ws += nPad * 128 * 2;
    ushort* WT = (ushort*)ws;                      ws += 6 * 16384 * 2;
    int* cursor = (int*)ws;                        ws += (size_t)n * 4;
    int* srcs   = (int*)ws;                        // n * CAP ints (12.8 MB)

    const int* srcrow = ei;
    const int* dstrow = ei + E;

    // prep: x->bf16 + 6 weight transposes + cursor zeroing
    int n4 = n * 128 / 4;
    int nzb = (n + 1023) / 1024;
    prep_kernel<<<6 + nzb + (n4 + 255) / 256, 256, 0, stream>>>(
        x, xb, n4, W1l, W1r, W2l, W2r, W3l, W3r, WT, cursor, nzb, n);

    // bucketed scatter (XCD-partitioned)
    scatter_part_kernel<<<2048, 256, 0, stream>>>(srcrow, dstrow, E, n, cursor, srcs);

    int gb = (int)(nPad / 64);
    int ab = (n + 15) / 16;

    // layer 1
    dual_gemm_mfma<<<gb, 256, 0, stream>>>(xb, WT + 0 * 16384, WT + 1 * 16384,
                                           b1l, b1r, XL, XR, n, sliceE);
    agg_head_kernel<<<2048, 256, 0, stream>>>(XL, XR, cursor, srcs, a1, c1, hb, n, sliceB);
    ln_relu_kernel<<<ab, 256, 0, stream>>>(hb, g1, be1, n);
    // layer 2
    dual_gemm_mfma<<<gb, 256, 0, stream>>>(hb, WT + 2 * 16384, WT + 3 * 16384,
                                           b2l, b2r, XL, XR, n, sliceE);
    agg_head_kernel<<<2048, 256, 0, stream>>>(XL, XR, cursor, srcs, a2, c2, hb, n, sliceB);
    ln_relu_kernel<<<ab, 256, 0, stream>>>(hb, g2, be2, n);
    // layer 3 (1 head, fused LN)
    dual_gemm_mfma<<<gb, 256, 0, stream>>>(hb, WT + 4 * 16384, WT + 5 * 16384,
                                           b3l, b3r, XL, XR, n, sliceE);
    aggregate3_kernel<<<ab, 256, 0, stream>>>(XL, XR, cursor, srcs, a3, c3, g3, be3,
                                              (float*)d_out, n, sliceB);
}